// Round 6
// baseline (124.554 us; speedup 1.0000x reference)
//
#include <hip/hip_runtime.h>
#include <math.h>

// Problem constants
#define DD 256
#define HH 8
#define AA 32
#define SS 512
#define BB 2
constexpr float BCONST      = 0.9f;
constexpr float ONE_MINUS_B = 0.1f;
constexpr float EPSF        = 1e-10f;
constexpr float SCALEF      = 0.0625f;   // 1/sqrt(256), exact power of 2
constexpr float FLTMAX      = 3.402823466e38f;

// Workspace layout (float offsets)
#define OFF_QKV    0
#define OFF_VP     786432
#define OFF_EW     1048576
#define OFF_PMIN   1310720
#define OFF_PMAX   1318912
#define OFF_VMIN   1327104
#define OFF_VRANGE 1327616
#define OFF_P      1328128

// Swizzled chunk buffer: row-major LD=32 floats, bank-quad ^= (row>>2)&7.
// All kb accesses are b128 at quad granularity, so the XOR keeps 16B align.
#define KB4(buf, row, col4) \
  (&(buf)[((row) << 5) | ((((col4) >> 2) ^ (((row) >> 2) & 7)) << 2)])

// ---------------------------------------------------------------------------
// Tiled fp32 GEMM (unchanged from R5): C[i][j] = dot(A[i,:K], Brow(j)).
// MM=true: V-column blocks also write per-row-tile min/max partials.
// ---------------------------------------------------------------------------
template<int TM, int TN, int RM, int RN, bool MM>
__global__ __launch_bounds__(256) void gemm_t(
    const float* __restrict__ A, const float* __restrict__ B0,
    const float* __restrict__ B1, int nsplit,
    float* __restrict__ C, int ldc, int K, int lda,
    float* __restrict__ pminP, float* __restrict__ pmaxP) {
  constexpr int LDT = 36;
  constexpr int CG  = TN / RN;
  constexpr int NA  = TM * 32 / 1024;
  constexpr int NB  = TN * 32 / 1024;
  __shared__ float As[TM][LDT];
  __shared__ float Bs[TN][LDT];
  const int i0 = blockIdx.x * TM;
  const int j0 = blockIdx.y * TN;
  const float* Bsrc = (j0 < nsplit) ? (B0 + (size_t)j0 * K)
                                    : (B1 + (size_t)(j0 - nsplit) * K);
  const int t  = threadIdx.x;
  const int lr = t >> 3;
  const int lc = (t & 7) << 2;
  const int tx = t % CG, ty = t / CG;

  float4 pa[NA], pb[NB];
#pragma unroll
  for (int u = 0; u < NA; ++u)
    pa[u] = *(const float4*)(A + (size_t)(i0 + lr + 32 * u) * lda + lc);
#pragma unroll
  for (int u = 0; u < NB; ++u)
    pb[u] = *(const float4*)(Bsrc + (size_t)(lr + 32 * u) * K + lc);

  float acc[RM][RN] = {};
  for (int k0 = 0; k0 < K; k0 += 32) {
    __syncthreads();
#pragma unroll
    for (int u = 0; u < NA; ++u) *(float4*)&As[lr + 32 * u][lc] = pa[u];
#pragma unroll
    for (int u = 0; u < NB; ++u) *(float4*)&Bs[lr + 32 * u][lc] = pb[u];
    __syncthreads();
    if (k0 + 32 < K) {
#pragma unroll
      for (int u = 0; u < NA; ++u)
        pa[u] = *(const float4*)(A + (size_t)(i0 + lr + 32 * u) * lda + k0 + 32 + lc);
#pragma unroll
      for (int u = 0; u < NB; ++u)
        pb[u] = *(const float4*)(Bsrc + (size_t)(lr + 32 * u) * K + k0 + 32 + lc);
    }
#pragma unroll
    for (int kk = 0; kk < 32; kk += 4) {
      float4 af[RM], bf[RN];
#pragma unroll
      for (int r = 0; r < RM; ++r) af[r] = *(const float4*)&As[ty * RM + r][kk];
#pragma unroll
      for (int c = 0; c < RN; ++c) bf[c] = *(const float4*)&Bs[tx + CG * c][kk];
#pragma unroll
      for (int r = 0; r < RM; ++r)
#pragma unroll
        for (int c = 0; c < RN; ++c)
          acc[r][c] += af[r].x * bf[c].x + af[r].y * bf[c].y +
                       af[r].z * bf[c].z + af[r].w * bf[c].w;
    }
  }
#pragma unroll
  for (int r = 0; r < RM; ++r)
#pragma unroll
    for (int c = 0; c < RN; ++c)
      C[(size_t)(i0 + ty * RM + r) * ldc + j0 + tx + CG * c] = acc[r][c];

  if (MM && j0 >= 512) {
    __syncthreads();
    float* mnb = &As[0][0];
    float* mxb = &Bs[0][0];
#pragma unroll
    for (int c = 0; c < RN; ++c) {
      float mn = acc[0][c], mx = acc[0][c];
#pragma unroll
      for (int r = 1; r < RM; ++r) {
        mn = fminf(mn, acc[r][c]);
        mx = fmaxf(mx, acc[r][c]);
      }
      mnb[(tx + CG * c) * 17 + ty] = mn;
      mxb[(tx + CG * c) * 17 + ty] = mx;
    }
    __syncthreads();
    if (t < TN) {
      float mn = mnb[t * 17], mx = mxb[t * 17];
#pragma unroll
      for (int i = 1; i < 16; ++i) {
        mn = fminf(mn, mnb[t * 17 + i]);
        mx = fmaxf(mx, mxb[t * 17 + i]);
      }
      const int bx = i0 >> 5;
      pminP[bx * 256 + (j0 - 512) + t] = mn;
      pmaxP[bx * 256 + (j0 - 512) + t] = mx;
    }
  }
}

// ---------------------------------------------------------------------------
// vp = expm1(p * log(v_norm)), computed ONCE (un-fused from attn: the fused
// version redid 2 transcendentals x 64 elems/thread x32 redundant blocks).
// Also writes vmin / vrange per (b,d) and pw.
// ---------------------------------------------------------------------------
__global__ __launch_bounds__(256) void vpk(
    const float* __restrict__ qkv, const float* __restrict__ pminP,
    const float* __restrict__ pmaxP, const float* __restrict__ p_param,
    float* __restrict__ vp, float* __restrict__ vminw,
    float* __restrict__ vrangew, float* __restrict__ pw) {
  const int blk = blockIdx.x;           // 0..1023
  const int b = blk >> 9, s = blk & 511;
  const int d = threadIdx.x;
  float mn = pminP[(b * 16) * 256 + d];
  float mx = pmaxP[(b * 16) * 256 + d];
#pragma unroll
  for (int c = 1; c < 16; ++c) {
    mn = fminf(mn, pminP[(b * 16 + c) * 256 + d]);
    mx = fmaxf(mx, pmaxP[(b * 16 + c) * 256 + d]);
  }
  float p = 50000.0f * tanhf(0.005f * p_param[d]) + 1.0f;
  if (p == 0.0f) p = 0.0001f;
  const float range = mx - mn + EPSF;
  const float v  = qkv[((size_t)(b * 512 + s)) * 768 + 512 + d];
  const float vn = (ONE_MINUS_B * (v - mn)) / range + BCONST;
  vp[(size_t)blk * 256 + d] = expm1f(p * logf(vn));
  if (s == 0) { vminw[b * 256 + d] = mn; vrangew[b * 256 + d] = range; }
  if (blk == 0) pw[d] = p;
}

// ---------------------------------------------------------------------------
// Fused attention. LDS geometry reworked for b128 quad spread:
//  - kb: XOR-swizzled (quad ^= (row>>2)&7, LD=32): kf/vf reads at floor.
//  - scT: scores TRANSPOSED [k][q], LD=20 (LD/4=5 odd): phase-3 reads the
//    4 q's of a micro-tile as one b128 on 4 distinct quads (2-way, free).
//  - epilogue: shfl_xor(32) folds intra-wave ks pair, 4-slice LDS reduce.
// grid = (B*H, S/16); 256 threads; 16 queries per block.
// ---------------------------------------------------------------------------
__global__ __launch_bounds__(256) void attn_k(
    const float* __restrict__ qkv, const float* __restrict__ vp,
    const float* __restrict__ pw, const float* __restrict__ vminw,
    const float* __restrict__ vrangew, float* __restrict__ ew) {
  __shared__ float qs[16][36];
  __shared__ float scT[512 * 20];      // [k][q] scores -> unnormalized e
  __shared__ float kb[256 * 32];       // swizzled K / VP chunk (reused: part2)
  __shared__ float red[16][17];        // [q][0..15]=partials, [q][16]=T
  const int bh  = blockIdx.x;
  const int b   = bh >> 3, h = bh & 7;
  const int q0g = blockIdx.y * 16;
  const int t   = threadIdx.x;
  const int ldr = t >> 3, ldc4 = (t & 7) << 2;

  if (t < 128) {                       // q tile, fold in SCALE (exact *2^-4)
    const int q = t >> 3, c4 = (t & 7) << 2;
    float4 qv = *(const float4*)(qkv + ((size_t)(b * 512 + q0g + q)) * 768 + h * 32 + c4);
    qv.x *= SCALEF; qv.y *= SCALEF; qv.z *= SCALEF; qv.w *= SCALEF;
    *(float4*)&qs[q][c4] = qv;
  }

  // prefetch K chunk 0
  float4 pk[8];
#pragma unroll
  for (int u = 0; u < 8; ++u)
    pk[u] = *(const float4*)(qkv + ((size_t)(b * 512 + ldr + 32 * u)) * 768 + 256 + h * 32 + ldc4);

  // ---- Phase 1: scores (16 x 512); thread owns q-rows qg*4..+3, k kg*4..+3
  const int qg = t & 3;
  const int kg = t >> 2;               // 0..63
  for (int kc = 0; kc < 2; ++kc) {
    __syncthreads();
#pragma unroll
    for (int u = 0; u < 8; ++u) *(float4*)KB4(kb, ldr + 32 * u, ldc4) = pk[u];
    __syncthreads();
    if (kc == 0) {                     // prefetch K chunk 1
#pragma unroll
      for (int u = 0; u < 8; ++u)
        pk[u] = *(const float4*)(qkv + ((size_t)(b * 512 + 256 + ldr + 32 * u)) * 768 + 256 + h * 32 + ldc4);
    } else {                           // prefetch VP chunk 0
#pragma unroll
      for (int u = 0; u < 8; ++u)
        pk[u] = *(const float4*)(vp + ((size_t)(b * 512 + ldr + 32 * u)) * 256 + h * 32 + ldc4);
    }
    float a2[4][4] = {};
#pragma unroll
    for (int kk = 0; kk < 32; kk += 4) {
      float4 qf[4], kf[4];
#pragma unroll
      for (int r = 0; r < 4; ++r) qf[r] = *(const float4*)&qs[qg * 4 + r][kk];
#pragma unroll
      for (int c = 0; c < 4; ++c) kf[c] = *(const float4*)KB4(kb, kg * 4 + c, kk);
#pragma unroll
      for (int r = 0; r < 4; ++r)
#pragma unroll
        for (int c = 0; c < 4; ++c)
          a2[r][c] += qf[r].x * kf[c].x + qf[r].y * kf[c].y +
                      qf[r].z * kf[c].z + qf[r].w * kf[c].w;
    }
    // transposed write: scT[k][qg*4..+3] (q contiguous per thread)
#pragma unroll
    for (int c = 0; c < 4; ++c)
      *(float4*)&scT[(kc * 256 + kg * 4 + c) * 20 + qg * 4] =
          make_float4(a2[0][c], a2[1][c], a2[2][c], a2[3][c]);
  }
  __syncthreads();

  // ---- Phase 2: 2-pass softmax; thread (q, j) owns k in [32j, 32j+32)
  {
    const int q = t & 15, j = t >> 4;
    float m = -FLTMAX;
#pragma unroll
    for (int i = 0; i < 32; ++i) m = fmaxf(m, scT[(j * 32 + i) * 20 + q]);
    red[q][j] = m;
    __syncthreads();
    float rm = red[q][0];
#pragma unroll
    for (int jj = 1; jj < 16; ++jj) rm = fmaxf(rm, red[q][jj]);
    __syncthreads();                   // all reads of maxes done
    float ls = 0.f;
#pragma unroll
    for (int i = 0; i < 32; ++i) {
      float e = __expf(scT[(j * 32 + i) * 20 + q] - rm);
      scT[(j * 32 + i) * 20 + q] = e;
      ls += e;
    }
    red[q][j] = ls;
    __syncthreads();
    if (j == 0) {
      float tot = 0.f;
#pragma unroll
      for (int jj = 0; jj < 16; ++jj) tot += red[q][jj];
      red[q][16] = tot;
    }
  }

  // ---- Phase 3: ACC[q][a] = sum_k e[q][k]*vp[k][a]; 4q x 4a, k-split 8
  float a3[4][4] = {};
  const int qg3 = t & 3;
  const int ag3 = (t >> 2) & 7;
  const int ks  = t >> 5;              // 0..7: slice ks*32..+31 per chunk
  for (int kc = 0; kc < 2; ++kc) {
    __syncthreads();
#pragma unroll
    for (int u = 0; u < 8; ++u) *(float4*)KB4(kb, ldr + 32 * u, ldc4) = pk[u];
    __syncthreads();
    if (kc == 0) {                     // prefetch VP chunk 1
#pragma unroll
      for (int u = 0; u < 8; ++u)
        pk[u] = *(const float4*)(vp + ((size_t)(b * 512 + 256 + ldr + 32 * u)) * 256 + h * 32 + ldc4);
    }
#pragma unroll
    for (int g = 0; g < 8; ++g) {
#pragma unroll
      for (int c = 0; c < 4; ++c) {
        const int k = ks * 32 + g * 4 + c;          // local k in chunk
        const float4 sq = *(const float4*)&scT[(kc * 256 + k) * 20 + qg3 * 4];
        const float4 vf = *(const float4*)KB4(kb, k, ag3 * 4);
        a3[0][0] += sq.x * vf.x; a3[0][1] += sq.x * vf.y; a3[0][2] += sq.x * vf.z; a3[0][3] += sq.x * vf.w;
        a3[1][0] += sq.y * vf.x; a3[1][1] += sq.y * vf.y; a3[1][2] += sq.y * vf.z; a3[1][3] += sq.y * vf.w;
        a3[2][0] += sq.z * vf.x; a3[2][1] += sq.z * vf.y; a3[2][2] += sq.z * vf.z; a3[2][3] += sq.z * vf.w;
        a3[3][0] += sq.w * vf.x; a3[3][1] += sq.w * vf.y; a3[3][2] += sq.w * vf.z; a3[3][3] += sq.w * vf.w;
      }
    }
  }

  // ---- ks-pair fold within wave (ks = 2w, 2w+1 both live in wave w),
  // then 4-slice (one per wave) reduction through LDS.
#pragma unroll
  for (int r = 0; r < 4; ++r)
#pragma unroll
    for (int c = 0; c < 4; ++c)
      a3[r][c] += __shfl_xor(a3[r][c], 32);
  __syncthreads();                     // kb reads done; reuse as part2
  float* part2 = &kb[0];               // [w4][520]
  if ((t & 32) == 0) {
    const int w = t >> 6;
#pragma unroll
    for (int r = 0; r < 4; ++r)
#pragma unroll
      for (int c = 0; c < 4; ++c)
        part2[w * 520 + (qg3 * 4 + r) * 32 + ag3 * 4 + c] = a3[r][c];
  }
  __syncthreads();
  {
    const int q = t >> 4, a = (t * 2) & 31;   // two consecutive a per thread
    const float invT = 1.0f / red[q][16];
    float o2[2];
#pragma unroll
    for (int o = 0; o < 2; ++o) {
      const int ia = q * 32 + a + o;
      float s = part2[ia] + part2[520 + ia] + part2[1040 + ia] + part2[1560 + ia];
      s *= invT;
      const int d = h * 32 + a + o;
      const float p = pw[d];
      const float mean = log1pf(s);         // log(sum sm * v^p), robust near 1
      const float en = expf(mean / p);      // robust as p -> 0
      o2[o] = (en - BCONST) * vrangew[b * 256 + d] / ONE_MINUS_B + vminw[b * 256 + d];
    }
    *(float2*)(ew + ((size_t)(b * 512 + q0g + q)) * 256 + h * 32 + a) =
        make_float2(o2[0], o2[1]);
  }
}

// ---------------------------------------------------------------------------
extern "C" void kernel_launch(void* const* d_in, const int* in_sizes, int n_in,
                              void* d_out, int out_size, void* d_ws, size_t ws_size,
                              hipStream_t stream) {
  const float* ctx  = (const float*)d_in[0];
  const float* WQ   = (const float*)d_in[1];
  const float* WKV  = (const float*)d_in[2];
  const float* WOUT = (const float*)d_in[3];
  const float* PP   = (const float*)d_in[4];
  float* ws      = (float*)d_ws;
  float* qkv     = ws + OFF_QKV;
  float* vp      = ws + OFF_VP;
  float* ew      = ws + OFF_EW;
  float* pminP   = ws + OFF_PMIN;
  float* pmaxP   = ws + OFF_PMAX;
  float* vminw   = ws + OFF_VMIN;
  float* vrangew = ws + OFF_VRANGE;
  float* pw      = ws + OFF_P;
  float* out     = (float*)d_out;

  // Fused Q|K|V projection + V min/max partials: 1024x768x256, 32x64 tiles
  gemm_t<32, 64, 2, 4, true><<<dim3(32, 12), 256, 0, stream>>>(
      ctx, WQ, WKV, 256, qkv, 768, 256, 256, pminP, pmaxP);
  // expm1(p * log(v_norm)) once + p vector + vmin/vrange
  vpk<<<1024, 256, 0, stream>>>(qkv, pminP, pmaxP, PP, vp, vminw, vrangew, pw);
  // Fused attention + power-mean epilogue
  attn_k<<<dim3(16, 32), 256, 0, stream>>>(qkv, vp, pw, vminw, vrangew, ew);
  // Output projection: 1024x256x256, 32x32 tiles
  gemm_t<32, 32, 2, 2, false><<<dim3(32, 8), 256, 0, stream>>>(
      ew, WOUT, WOUT, 1 << 30, out, 256, 256, 256, nullptr, nullptr);
}